// Round 11
// baseline (435.034 us; speedup 1.0000x reference)
//
#include <hip/hip_runtime.h>

#define B_    4
#define N_    50000
#define E_    800000
#define FIN_  128
#define F_    64
#define BN_   (B_ * N_)        // 200000
#define TOT_  (BN_ * F_)       // 12,800,000
#define BE_   (B_ * E_)        // 3,200,000
#define ALPHA_ 0.2f
#define NEG_BIG_ -9.0e15f

#define XS_STRIDE 132
#define GEMM_BLOCKS (BN_ / 64)     // 3125
#define COUNT_BLOCKS (BE_ / 1024)  // 3125 (4 edges/thread)

#define MAXDEG_ 28                 // deg = 1+Pois(15); P(deg>28) ~ 6e-4
#define OVFCAP_ 16384              // ~50x margin over expected overflow

__device__ __forceinline__ float bf2f(unsigned int u16) {
    union { unsigned int i; float f; } v;
    v.i = u16 << 16;
    return v.f;
}
__device__ __forceinline__ unsigned int f2bf(float f) {
    union { float f; unsigned int u; } v;
    v.f = f;
    unsigned int r = v.u + 0x7FFFu + ((v.u >> 16) & 1u);  // RNE
    return r >> 16;
}

// ---- Kernel 1: fused [gemm | count+ELL-place], roles by bid&1 -------------
// gemm role:  h = X@W (bf16 packed -> hq), e1/e2 (fp32). (r2-proven form)
// count role: 4 independent atomicAdds issued back-to-back (one latency
//             exposure, not four), then rank-dependent u16 ell stores.
__global__ __launch_bounds__(256) void gemm_count_kernel(
    const float* __restrict__ X,
    const float* __restrict__ W,
    const float* __restrict__ a,
    const int* __restrict__ edges,
    unsigned short* __restrict__ hq,
    float* __restrict__ e1,
    float* __restrict__ e2,
    int* __restrict__ cnt,
    unsigned short* __restrict__ ell,
    int* __restrict__ ovfc,
    int2* __restrict__ ovf) {
    __shared__ float Wf[FIN_ * F_];            // 32 KB
    __shared__ float Xs[64 * XS_STRIDE];       // 33.8 KB

    const int tid = threadIdx.x;
    const int bid = blockIdx.x;

    if (bid & 1) {
        // -------- count+place role: 4 edges per thread --------
        const int g  = (bid >> 1) * 256 + tid;     // 0 .. BE_/4
        const int ge = g * 4;
        const int b  = ge / E_;
        const int e  = ge - b * E_;
        const int4 s4 = *(const int4*)&edges[(size_t)b * 2 * E_ + e];
        const int4 d4 = *(const int4*)&edges[(size_t)b * 2 * E_ + E_ + e];
        const int gsv[4] = { b * N_ + s4.x, b * N_ + s4.y,
                             b * N_ + s4.z, b * N_ + s4.w };
        const int dd[4] = { d4.x, d4.y, d4.z, d4.w };
        int r[4];
        // 4 independent atomics in flight before any dependent use
        r[0] = atomicAdd(&cnt[gsv[0]], 1);
        r[1] = atomicAdd(&cnt[gsv[1]], 1);
        r[2] = atomicAdd(&cnt[gsv[2]], 1);
        r[3] = atomicAdd(&cnt[gsv[3]], 1);
#pragma unroll
        for (int j = 0; j < 4; ++j) {
            if (r[j] < MAXDEG_) {
                ell[(size_t)gsv[j] * MAXDEG_ + r[j]] = (unsigned short)dd[j];
            } else {
                const int i = atomicAdd(ovfc, 1);
                if (i < OVFCAP_) ovf[i] = make_int2(gsv[j], dd[j]);
            }
        }
        return;
    }

    // ---------------- gemm role ----------------
    const float4* Wg = (const float4*)W;
    for (int i = tid; i < 2048; i += 256)
        ((float4*)Wf)[i] = Wg[i];

    const int row0 = (bid >> 1) * 64;
    const float4* Xg = (const float4*)(X + (size_t)row0 * FIN_);
    for (int i = tid; i < 2048; i += 256) {
        const int r = i >> 5;
        const int c = i & 31;
        float4 v = Xg[i];
        *(float4*)&Xs[r * XS_STRIDE + c * 4] = v;
    }
    __syncthreads();

    const int cg = tid & 15;
    const int rg = tid >> 4;

    float acc[4][4] = {};
#pragma unroll 4
    for (int k = 0; k < FIN_; ++k) {
        const float4 wv = *(const float4*)&Wf[k * F_ + cg * 4];
        float xr[4];
#pragma unroll
        for (int j = 0; j < 4; ++j)
            xr[j] = Xs[(rg * 4 + j) * XS_STRIDE + k];
#pragma unroll
        for (int j = 0; j < 4; ++j) {
            acc[j][0] += xr[j] * wv.x;
            acc[j][1] += xr[j] * wv.y;
            acc[j][2] += xr[j] * wv.z;
            acc[j][3] += xr[j] * wv.w;
        }
    }

    float a1v[4], a2v[4];
#pragma unroll
    for (int i = 0; i < 4; ++i) {
        a1v[i] = a[cg * 4 + i];
        a2v[i] = a[F_ + cg * 4 + i];
    }

#pragma unroll
    for (int j = 0; j < 4; ++j) {
        const int row = row0 + rg * 4 + j;
        union { ushort4 v; unsigned short s[4]; } st;
#pragma unroll
        for (int i = 0; i < 4; ++i) st.s[i] = (unsigned short)f2bf(acc[j][i]);
        *(ushort4*)&hq[(size_t)row * F_ + cg * 4] = st.v;   // 8B-aligned

        float p1 = acc[j][0] * a1v[0] + acc[j][1] * a1v[1] +
                   acc[j][2] * a1v[2] + acc[j][3] * a1v[3];
        float p2 = acc[j][0] * a2v[0] + acc[j][1] * a2v[1] +
                   acc[j][2] * a2v[2] + acc[j][3] * a2v[3];
#pragma unroll
        for (int m = 8; m >= 1; m >>= 1) {
            p1 += __shfl_xor(p1, m);
            p2 += __shfl_xor(p2, m);
        }
        if (cg == 0) { e1[row] = p1; e2[row] = p2; }
    }
}

// ---- Kernel 2: gather from ELL + weight + normalize + elu. ---------------
// Wave per node, 8 edge-groups x 8 lanes, uint4/lane. ALL loads issue
// unconditionally (ell zero-init: invalid slots -> dst 0, a hot row);
// validity is applied post-load as wt = valid ? wt : 0. Dependence chain
// is [cnt || ell] -> hq/e2 -> masked accumulate (2 levels, not 3).
struct Acc9 {
    float a0, a1, a2, a3, a4, a5, a6, a7, rs;
    __device__ __forceinline__ void add(float wt, const uint4& p) {
        a0 += wt * bf2f(p.x & 0xFFFFu); a1 += wt * bf2f(p.x >> 16);
        a2 += wt * bf2f(p.y & 0xFFFFu); a3 += wt * bf2f(p.y >> 16);
        a4 += wt * bf2f(p.z & 0xFFFFu); a5 += wt * bf2f(p.z >> 16);
        a6 += wt * bf2f(p.w & 0xFFFFu); a7 += wt * bf2f(p.w >> 16);
        rs += wt;
    }
};

__global__ __launch_bounds__(256) void gather_kernel(
    const int* __restrict__ cnt,
    const unsigned short* __restrict__ ell,
    const int* __restrict__ ovfc,
    const int2* __restrict__ ovf,
    const float* __restrict__ e1,
    const float* __restrict__ e2,
    const uint4* __restrict__ hq4,   // packed bf16, [BN][8] uint4
    float* __restrict__ out) {
    const int tid = threadIdx.x;
    const int lane = tid & 63;
    const int grp = lane >> 3;       // 0..7 edge group
    const int sub = lane & 7;        // 0..7 feature octet
    const int gs = (int)((blockIdx.x * 256 + tid) >> 6);  // 0..BN_ (exact)
    const int b = gs / N_;
    const uint4* hb = hq4 + (size_t)b * N_ * 8;
    const float* e2b = e2 + b * N_;
    const int cv = cnt[gs];
    const float e1s = e1[gs];
    const unsigned short* eb = ell + (size_t)gs * MAXDEG_;

    // unconditional slot dsts (zero-init => safe); grp>=4 slot3 -> hot row 0
    const int d0 = eb[grp];
    const int d1 = eb[grp + 8];
    const int d2 = eb[grp + 16];
    const int d3 = (grp < 4) ? (int)eb[grp + 24] : 0;

    // unconditional row + e2 loads (invalid -> row 0 / e2[0], L2-hot)
    const uint4 p0 = hb[(size_t)d0 * 8 + sub];
    const uint4 p1 = hb[(size_t)d1 * 8 + sub];
    const uint4 p2 = hb[(size_t)d2 * 8 + sub];
    const uint4 p3 = hb[(size_t)d3 * 8 + sub];
    const float s0 = e1s + e2b[d0];
    const float s1 = e1s + e2b[d1];
    const float s2 = e1s + e2b[d2];
    const float s3 = e1s + e2b[d3];

    const int dm = cv < MAXDEG_ ? cv : MAXDEG_;
    float w0 = __expf(-(s0 > 0.0f ? s0 : ALPHA_ * s0));
    float w1 = __expf(-(s1 > 0.0f ? s1 : ALPHA_ * s1));
    float w2 = __expf(-(s2 > 0.0f ? s2 : ALPHA_ * s2));
    float w3 = __expf(-(s3 > 0.0f ? s3 : ALPHA_ * s3));
    w0 = (grp < dm) ? w0 : 0.0f;          // validity applied post-load
    w1 = (grp + 8 < dm) ? w1 : 0.0f;
    w2 = (grp + 16 < dm) ? w2 : 0.0f;
    w3 = (grp + 24 < dm) ? w3 : 0.0f;     // auto-false for grp>=4

    Acc9 ac = {};
    ac.add(w0, p0);
    ac.add(w1, p1);
    ac.add(w2, p2);
    ac.add(w3, p3);

    // rare overflow path: scan spill list (tiny, L2-hot)
    if (cv > MAXDEG_) {
        int no = *ovfc;
        if (no > OVFCAP_) no = OVFCAP_;
        for (int i = 0; i < no; ++i) {
            const int2 t = ovf[i];
            if (t.x == gs) {
                const float sv = e1s + e2b[t.y];
                const float lr = sv > 0.0f ? sv : ALPHA_ * sv;
                const float wt = __expf(-lr);
                if (grp == 0) {
                    const uint4 p = hb[(size_t)t.y * 8 + sub];
                    ac.add(wt, p);
                }
            }
        }
    }

    // reduce across the 8 edge groups (xor masks flip grp bits 3,4,5)
#pragma unroll
    for (int m = 8; m <= 32; m <<= 1) {
        ac.a0 += __shfl_xor(ac.a0, m); ac.a1 += __shfl_xor(ac.a1, m);
        ac.a2 += __shfl_xor(ac.a2, m); ac.a3 += __shfl_xor(ac.a3, m);
        ac.a4 += __shfl_xor(ac.a4, m); ac.a5 += __shfl_xor(ac.a5, m);
        ac.a6 += __shfl_xor(ac.a6, m); ac.a7 += __shfl_xor(ac.a7, m);
        ac.rs += __shfl_xor(ac.rs, m);
    }

    if (grp == 0) {
        const float rs = ac.rs;
        float v[8] = { ac.a0 / rs, ac.a1 / rs, ac.a2 / rs, ac.a3 / rs,
                       ac.a4 / rs, ac.a5 / rs, ac.a6 / rs, ac.a7 / rs };
        float o[8];
#pragma unroll
        for (int j = 0; j < 8; ++j) {
            float x = v[j];
            if (x != x) x = NEG_BIG_;
            o[j] = x > 0.0f ? x : (__expf(x) - 1.0f);
        }
        float* po = &out[(size_t)gs * F_ + sub * 8];
        *(float4*)&po[0] = make_float4(o[0], o[1], o[2], o[3]);
        *(float4*)&po[4] = make_float4(o[4], o[5], o[6], o[7]);
    }
}

extern "C" void kernel_launch(void* const* d_in, const int* in_sizes, int n_in,
                              void* d_out, int out_size, void* d_ws, size_t ws_size,
                              hipStream_t stream) {
    const float* X = (const float*)d_in[0];
    const int* edges = (const int*)d_in[1];
    const float* W = (const float*)d_in[2];
    const float* a = (const float*)d_in[3];
    float* out = (float*)d_out;

    // ws layout (~39.4 MB, proven >= 53.6 MB available):
    // [e1 BN f32][e2 BN f32][hq BN*64 bf16][cnt BN i32][ovfc 4 i32]
    // [ell (BN*28+8) u16][ovf OVFCAP int2]
    // cnt..ell contiguous -> single ~12 MB memset zeroes cnt+ovfc+ell.
    float* e1 = (float*)d_ws;
    float* e2 = e1 + BN_;
    unsigned short* hq = (unsigned short*)(e2 + BN_);
    int* cnt = (int*)(hq + (size_t)BN_ * F_);
    int* ovfc = cnt + BN_;
    unsigned short* ell = (unsigned short*)(ovfc + 4);
    int2* ovf = (int2*)(ell + (size_t)BN_ * MAXDEG_ + 8);

    const size_t zbytes = (size_t)BN_ * sizeof(int) + 4 * sizeof(int) +
                          ((size_t)BN_ * MAXDEG_ + 8) * sizeof(unsigned short);
    (void)hipMemsetAsync(cnt, 0, zbytes, stream);

    gemm_count_kernel<<<GEMM_BLOCKS + COUNT_BLOCKS, 256, 0, stream>>>(
        X, W, a, edges, hq, e1, e2, cnt, ell, ovfc, ovf);
    gather_kernel<<<BN_ / 4, 256, 0, stream>>>(
        cnt, ell, ovfc, ovf, e1, e2, (const uint4*)hq, out);
}